// Round 3
// baseline (101.841 us; speedup 1.0000x reference)
//
#include <hip/hip_runtime.h>
#include <hip/hip_bf16.h>

typedef __attribute__((ext_vector_type(4))) float f32x4;
typedef __attribute__((ext_vector_type(8))) short s16x8;

static constexpr int Bn = 32;
static constexpr int Tn = 4096;
static constexpr int Dn = 256;
static constexpr int Un = 256;
static constexpr int CTX_C = 16;

// fp32 -> bf16 round-to-nearest-even
__device__ __forceinline__ ushort f2bf(float f) {
    unsigned x = __float_as_uint(f);
    x += 0x7fffu + ((x >> 16) & 1u);
    return (ushort)(x >> 16);
}

// stable fast tanh: tanh(x) = sign(x) * (1 - e) / (1 + e), e = exp(-2|x|)
__device__ __forceinline__ float fast_tanh(float x) {
    float ax = fabsf(x);
    float e = __expf(-2.0f * ax);
    float r = __fdividef(1.0f - e, 1.0f + e);
    return copysignf(r, x);
}

__device__ __forceinline__ void gload_lds16(const void* g, void* l) {
    __builtin_amdgcn_global_load_lds(
        (const __attribute__((address_space(1))) unsigned*)g,
        (__attribute__((address_space(3))) unsigned*)l, 16, 0, 0);
}

// K0: W1T[u][d] = bf16(W1[d][u])
__global__ __launch_bounds__(256) void k_w1t(const float* __restrict__ W1,
                                             ushort* __restrict__ W1T) {
    const int u = blockIdx.x, d = threadIdx.x;
    W1T[u * Dn + d] = f2bf(W1[d * Un + u]);
}

// K1: qb[b][u] = sum_d query[b][d]*W2[d][u] + b1[u] + b2[u]
__global__ __launch_bounds__(256) void k_qproj(const float* __restrict__ query,
                                               const float* __restrict__ W2,
                                               const float* __restrict__ b1,
                                               const float* __restrict__ b2,
                                               float* __restrict__ qb) {
    __shared__ float qs[Dn];
    const int b = blockIdx.x, u = threadIdx.x;
    qs[u] = query[b * Dn + u];
    __syncthreads();
    float acc = b1[u] + b2[u];
    #pragma unroll 8
    for (int d = 0; d < Dn; ++d) acc += qs[d] * W2[d * Un + u];
    qb[b * Un + u] = acc;
}

// K2: MFMA score GEMM. Block: 64t x 256u, 4 waves; wave w owns 64t x 64u
// (acc[4][4] f32x4). Bl double-buffered, chunk-XOR swizzled (storage chunk
// cs holds data chunk cs ^ ((u>>1)&3)); global source pre-swizzled so the
// gload_lds dest stays linear (m173 both-sides pattern). Read swizzle
// swz = hi ^ ((l15>>1)&3) => 2 lanes/bank (free). One barrier per k-chunk.
__global__ __launch_bounds__(256, 2) void k_score(const float* __restrict__ values,
                                                  const ushort* __restrict__ W1T,
                                                  const float* __restrict__ qb,
                                                  const float* __restrict__ Vw,
                                                  const float* __restrict__ bV,
                                                  float* __restrict__ scores) {
    __shared__ __align__(16) ushort Al[64][264];      // 33.8 KB, 528B rows -> 2-way
    __shared__ __align__(16) ushort Bl[2][256][32];   // 32 KB dbuf
    __shared__ float sred[4][64];                     // cross-wave u-reduction
    const int tid = threadIdx.x;
    const int b = blockIdx.y;
    const int t0 = blockIdx.x * 64;
    const int wid = tid >> 6;
    const int lane = tid & 63;
    const int l15 = lane & 15;
    const int hi = lane >> 4;
    const int swz = hi ^ ((l15 >> 1) & 3);

    // per-wave epilogue vectors: u = wid*64 + ut*16 + l15
    float Vreg[4], qreg[4];
    #pragma unroll
    for (int ut = 0; ut < 4; ++ut) {
        int u = wid * 64 + ut * 16 + l15;
        Vreg[ut] = Vw[u];
        qreg[ut] = qb[b * Un + u];
    }

    // Stage A: 64 rows x 256 d, fp32 coalesced -> bf16 -> LDS
    const float* vbase = values + ((size_t)b * Tn + t0) * Dn;
    #pragma unroll
    for (int i = 0; i < 8; ++i) {
        int flat = i * 2048 + tid * 8;
        int row = flat >> 8, col = flat & 255;
        const float4 f0 = *(const float4*)&vbase[row * Dn + col];
        const float4 f1 = *(const float4*)&vbase[row * Dn + col + 4];
        s16x8 p;
        p[0] = (short)f2bf(f0.x); p[1] = (short)f2bf(f0.y);
        p[2] = (short)f2bf(f0.z); p[3] = (short)f2bf(f0.w);
        p[4] = (short)f2bf(f1.x); p[5] = (short)f2bf(f1.y);
        p[6] = (short)f2bf(f1.z); p[7] = (short)f2bf(f1.w);
        *(s16x8*)&Al[row][col] = p;
    }

    // Stage B chunk kc into Bl[buf]; source chunk pre-swizzled.
    auto stage_b = [&](int kc, int buf) {
        #pragma unroll
        for (int j = 0; j < 4; ++j) {
            int f = j * 256 + tid;
            int u = f >> 2, cs = f & 3;
            int cd = cs ^ ((u >> 1) & 3);
            const ushort* gsrc = W1T + u * Dn + kc * 32 + cd * 8;
            ushort* ldst = &Bl[buf][0][0] + (size_t)(j * 256 + (tid & ~63)) * 8;
            gload_lds16(gsrc, ldst);
        }
    };

    stage_b(0, 0);

    f32x4 acc[4][4];
    #pragma unroll
    for (int tt = 0; tt < 4; ++tt)
        #pragma unroll
        for (int ut = 0; ut < 4; ++ut) acc[tt][ut] = (f32x4){0.f, 0.f, 0.f, 0.f};

    __syncthreads();  // A staged (lgkm) + B chunk0 staged (vmcnt)

    int cur = 0;
    for (int kc = 0; kc < 8; ++kc) {
        if (kc < 7) stage_b(kc + 1, cur ^ 1);
        const int k0 = kc * 32;
        s16x8 af[4], bfm[4];
        #pragma unroll
        for (int tt = 0; tt < 4; ++tt)
            af[tt] = *(const s16x8*)&Al[tt * 16 + l15][k0 + hi * 8];
        #pragma unroll
        for (int ut = 0; ut < 4; ++ut)
            bfm[ut] = *(const s16x8*)&Bl[cur][wid * 64 + ut * 16 + l15][swz * 8];
        #pragma unroll
        for (int tt = 0; tt < 4; ++tt)
            #pragma unroll
            for (int ut = 0; ut < 4; ++ut)
                acc[tt][ut] = __builtin_amdgcn_mfma_f32_16x16x32_bf16(af[tt], bfm[ut], acc[tt][ut], 0, 0, 0);
        __syncthreads();  // drains vmcnt (next chunk ready) + all waves done with cur
        cur ^= 1;
    }

    // Epilogue: acc[tt][ut][i] = proj[t=t0+tt*16+hi*4+i][u=wid*64+ut*16+l15]
    float ps[4][4];
    #pragma unroll
    for (int tt = 0; tt < 4; ++tt)
        #pragma unroll
        for (int i = 0; i < 4; ++i) ps[tt][i] = 0.f;
    #pragma unroll
    for (int tt = 0; tt < 4; ++tt)
        #pragma unroll
        for (int ut = 0; ut < 4; ++ut)
            #pragma unroll
            for (int i = 0; i < 4; ++i)
                ps[tt][i] += fast_tanh(acc[tt][ut][i] + qreg[ut]) * Vreg[ut];

    #pragma unroll
    for (int tt = 0; tt < 4; ++tt)
        #pragma unroll
        for (int i = 0; i < 4; ++i) {
            float v = ps[tt][i];
            v += __shfl_xor(v, 1, 64);
            v += __shfl_xor(v, 2, 64);
            v += __shfl_xor(v, 4, 64);
            v += __shfl_xor(v, 8, 64);
            if (l15 == 0) sred[wid][tt * 16 + hi * 4 + i] = v;
        }
    __syncthreads();
    if (tid < 64) {
        float s = sred[0][tid] + sred[1][tid] + sred[2][tid] + sred[3][tid] + bV[0];
        scores[b * Tn + t0 + tid] = s;
    }
}

// K3: softmax over T per batch, in place.
__global__ __launch_bounds__(256) void k_softmax(const float* __restrict__ scores,
                                                 float* __restrict__ attn) {
    const int b = blockIdx.x, tid = threadIdx.x;
    __shared__ float redm[4];
    __shared__ float reds[4];
    float s[16];
    float m = -1e30f;
    #pragma unroll
    for (int k = 0; k < 16; ++k) {
        s[k] = scores[b * Tn + k * 256 + tid];
        m = fmaxf(m, s[k]);
    }
    #pragma unroll
    for (int off = 32; off > 0; off >>= 1) m = fmaxf(m, __shfl_xor(m, off, 64));
    const int wid = tid >> 6;
    if ((tid & 63) == 0) redm[wid] = m;
    __syncthreads();
    m = fmaxf(fmaxf(redm[0], redm[1]), fmaxf(redm[2], redm[3]));
    float sum = 0.f;
    #pragma unroll
    for (int k = 0; k < 16; ++k) { s[k] = __expf(s[k] - m); sum += s[k]; }
    #pragma unroll
    for (int off = 32; off > 0; off >>= 1) sum += __shfl_xor(sum, off, 64);
    if ((tid & 63) == 0) reds[wid] = sum;
    __syncthreads();
    sum = reds[0] + reds[1] + reds[2] + reds[3];
    const float inv = 1.0f / sum;
    #pragma unroll
    for (int k = 0; k < 16; ++k) attn[b * Tn + k * 256 + tid] = s[k] * inv;
}

// K4: context partials, deterministic.
__global__ __launch_bounds__(256) void k_ctx_partial(const float* __restrict__ values,
                                                     const float* __restrict__ attn,
                                                     float* __restrict__ partial) {
    const int c = blockIdx.x, b = blockIdx.y, tid = threadIdx.x;
    const int d4 = (tid & 63) * 4, tg = tid >> 6;
    float4 a = make_float4(0.f, 0.f, 0.f, 0.f);
    const float* vbase = values + (size_t)b * Tn * Dn;
    const int tstart = c * (Tn / CTX_C);
    for (int t = tstart + tg; t < tstart + Tn / CTX_C; t += 4) {
        const float w = attn[b * Tn + t];  // wave-uniform
        const float4 v = *(const float4*)&vbase[(size_t)t * Dn + d4];
        a.x += w * v.x; a.y += w * v.y; a.z += w * v.z; a.w += w * v.w;
    }
    __shared__ float4 red[4][64];
    red[tg][tid & 63] = a;
    __syncthreads();
    if (tg == 0) {
        const float4 r0 = red[0][tid], r1 = red[1][tid], r2 = red[2][tid], r3 = red[3][tid];
        a.x = r0.x + r1.x + r2.x + r3.x;
        a.y = r0.y + r1.y + r2.y + r3.y;
        a.z = r0.z + r1.z + r2.z + r3.z;
        a.w = r0.w + r1.w + r2.w + r3.w;
        *(float4*)&partial[((size_t)b * CTX_C + c) * Dn + d4] = a;
    }
}

// K5: reduce the CTX_C partials per batch.
__global__ __launch_bounds__(256) void k_ctx_final(const float* __restrict__ partial,
                                                   float* __restrict__ context) {
    const int b = blockIdx.x, d = threadIdx.x;
    float a = 0.f;
    #pragma unroll
    for (int c = 0; c < CTX_C; ++c) a += partial[((size_t)b * CTX_C + c) * Dn + d];
    context[b * Dn + d] = a;
}

extern "C" void kernel_launch(void* const* d_in, const int* in_sizes, int n_in,
                              void* d_out, int out_size, void* d_ws, size_t ws_size,
                              hipStream_t stream) {
    const float* query  = (const float*)d_in[0];
    const float* values = (const float*)d_in[1];
    const float* W1     = (const float*)d_in[2];
    const float* b1     = (const float*)d_in[3];
    const float* W2     = (const float*)d_in[4];
    const float* b2     = (const float*)d_in[5];
    const float* Vw     = (const float*)d_in[6];
    const float* bV     = (const float*)d_in[7];

    float* context = (float*)d_out;            // [B,D]
    float* attn    = (float*)d_out + Bn * Dn;  // [B,T,1] — score scratch then softmax in place
    float*  partial = (float*)d_ws;                         // [B, CTX_C, D]
    float*  qb      = partial + Bn * CTX_C * Dn;            // [B, U]
    ushort* W1T     = (ushort*)(qb + Bn * Un);              // [U, D] bf16

    k_w1t<<<dim3(Un), dim3(Dn), 0, stream>>>(W1, W1T);
    k_qproj<<<dim3(Bn), dim3(256), 0, stream>>>(query, W2, b1, b2, qb);
    k_score<<<dim3(Tn / 64, Bn), dim3(256), 0, stream>>>(values, W1T, qb, Vw, bV, attn);
    k_softmax<<<dim3(Bn), dim3(256), 0, stream>>>(attn, attn);
    k_ctx_partial<<<dim3(CTX_C, Bn), dim3(256), 0, stream>>>(values, attn, partial);
    k_ctx_final<<<dim3(Bn), dim3(256), 0, stream>>>(partial, context);
}

// Round 4
// 98.310 us; speedup vs baseline: 1.0359x; 1.0359x over previous
//
#include <hip/hip_runtime.h>
#include <hip/hip_bf16.h>

typedef __attribute__((ext_vector_type(4))) float f32x4;
typedef __attribute__((ext_vector_type(8))) short s16x8;

static constexpr int Bn = 32;
static constexpr int Tn = 4096;
static constexpr int Dn = 256;
static constexpr int Un = 256;
static constexpr int CTX_C = 16;

// fp32 -> bf16 round-to-nearest-even
__device__ __forceinline__ ushort f2bf(float f) {
    unsigned x = __float_as_uint(f);
    x += 0x7fffu + ((x >> 16) & 1u);
    return (ushort)(x >> 16);
}

// stable fast tanh: tanh(x) = sign(x) * (1 - e) / (1 + e), e = exp(-2|x|)
__device__ __forceinline__ float fast_tanh(float x) {
    float ax = fabsf(x);
    float e = __expf(-2.0f * ax);
    float r = __fdividef(1.0f - e, 1.0f + e);
    return copysignf(r, x);
}

// K0: W1T[u][d] = bf16(W1[d][u])
__global__ __launch_bounds__(256) void k_w1t(const float* __restrict__ W1,
                                             ushort* __restrict__ W1T) {
    const int u = blockIdx.x, d = threadIdx.x;
    W1T[u * Dn + d] = f2bf(W1[d * Un + u]);
}

// K1: qb[b][u] = sum_d query[b][d]*W2[d][u] + b1[u] + b2[u]
__global__ __launch_bounds__(256) void k_qproj(const float* __restrict__ query,
                                               const float* __restrict__ W2,
                                               const float* __restrict__ b1,
                                               const float* __restrict__ b2,
                                               float* __restrict__ qb) {
    __shared__ float qs[Dn];
    const int b = blockIdx.x, u = threadIdx.x;
    qs[u] = query[b * Dn + u];
    __syncthreads();
    float acc = b1[u] + b2[u];
    #pragma unroll 8
    for (int d = 0; d < Dn; ++d) acc += qs[d] * W2[d * Un + u];
    qb[b * Un + u] = acc;
}

// K2: MFMA score GEMM, occupancy-first. Block: 64t x 256u, 4 waves; wave owns
// 64t x 64u (acc[4][4]). A staged ONCE to LDS (full K, 528B rows = balanced
// banks); B fragments stream global->register from L2-hot W1T with a one-chunk
// software pipeline. ZERO barriers in the k-loop. LDS 34.8 KB -> 4 blocks/CU,
// VGPR capped at 128 via launch_bounds(256,4).
__global__ __launch_bounds__(256, 4) void k_score(const float* __restrict__ values,
                                                  const ushort* __restrict__ W1T,
                                                  const float* __restrict__ qb,
                                                  const float* __restrict__ Vw,
                                                  const float* __restrict__ bV,
                                                  float* __restrict__ scores) {
    __shared__ __align__(16) ushort Al[64][264];   // 33.8 KB
    __shared__ float sred[4][64];                  // 1 KB cross-wave u-reduction
    const int tid = threadIdx.x;
    const int b = blockIdx.y;
    const int t0 = blockIdx.x * 64;
    const int wid = tid >> 6;
    const int lane = tid & 63;
    const int l15 = lane & 15;
    const int hi = lane >> 4;

    // Stage A: 64 rows x 256 d, fp32 coalesced -> bf16 -> LDS
    const float* vbase = values + ((size_t)b * Tn + t0) * Dn;
    #pragma unroll
    for (int i = 0; i < 8; ++i) {
        int flat = i * 2048 + tid * 8;
        int row = flat >> 8, col = flat & 255;
        const float4 f0 = *(const float4*)&vbase[row * Dn + col];
        const float4 f1 = *(const float4*)&vbase[row * Dn + col + 4];
        s16x8 p;
        p[0] = (short)f2bf(f0.x); p[1] = (short)f2bf(f0.y);
        p[2] = (short)f2bf(f0.z); p[3] = (short)f2bf(f0.w);
        p[4] = (short)f2bf(f1.x); p[5] = (short)f2bf(f1.y);
        p[6] = (short)f2bf(f1.z); p[7] = (short)f2bf(f1.w);
        *(s16x8*)&Al[row][col] = p;
    }

    // B fragment base for this lane: rows u = wid*64 + ut*16 + l15, k-chunk hi
    const ushort* wbase = W1T + (size_t)(wid * 64 + l15) * Dn + hi * 8;

    f32x4 acc[4][4];
    #pragma unroll
    for (int tt = 0; tt < 4; ++tt)
        #pragma unroll
        for (int ut = 0; ut < 4; ++ut) acc[tt][ut] = (f32x4){0.f, 0.f, 0.f, 0.f};

    // prefetch B chunk 0
    s16x8 bfn[4];
    #pragma unroll
    for (int ut = 0; ut < 4; ++ut)
        bfn[ut] = *(const s16x8*)&wbase[(size_t)ut * 16 * Dn];

    __syncthreads();  // A tile visible to all waves

    for (int kc = 0; kc < 8; ++kc) {
        s16x8 bf[4];
        #pragma unroll
        for (int ut = 0; ut < 4; ++ut) bf[ut] = bfn[ut];
        if (kc < 7) {
            #pragma unroll
            for (int ut = 0; ut < 4; ++ut)
                bfn[ut] = *(const s16x8*)&wbase[(size_t)ut * 16 * Dn + (kc + 1) * 32];
        }
        const int k0 = kc * 32;
        #pragma unroll
        for (int tt = 0; tt < 4; ++tt) {
            const s16x8 af = *(const s16x8*)&Al[tt * 16 + l15][k0 + hi * 8];
            #pragma unroll
            for (int ut = 0; ut < 4; ++ut)
                acc[tt][ut] = __builtin_amdgcn_mfma_f32_16x16x32_bf16(af, bf[ut], acc[tt][ut], 0, 0, 0);
        }
    }

    // epilogue vectors loaded AFTER the k-loop (keeps loop VGPR pressure low)
    float Vreg[4], qreg[4];
    #pragma unroll
    for (int ut = 0; ut < 4; ++ut) {
        int u = wid * 64 + ut * 16 + l15;
        Vreg[ut] = Vw[u];
        qreg[ut] = qb[b * Un + u];
    }

    // acc[tt][ut][i] = proj[t = t0+tt*16+hi*4+i][u = wid*64+ut*16+l15]
    float ps[4][4];
    #pragma unroll
    for (int tt = 0; tt < 4; ++tt)
        #pragma unroll
        for (int i = 0; i < 4; ++i) ps[tt][i] = 0.f;
    #pragma unroll
    for (int tt = 0; tt < 4; ++tt)
        #pragma unroll
        for (int ut = 0; ut < 4; ++ut)
            #pragma unroll
            for (int i = 0; i < 4; ++i)
                ps[tt][i] += fast_tanh(acc[tt][ut][i] + qreg[ut]) * Vreg[ut];

    #pragma unroll
    for (int tt = 0; tt < 4; ++tt)
        #pragma unroll
        for (int i = 0; i < 4; ++i) {
            float v = ps[tt][i];
            v += __shfl_xor(v, 1, 64);
            v += __shfl_xor(v, 2, 64);
            v += __shfl_xor(v, 4, 64);
            v += __shfl_xor(v, 8, 64);
            if (l15 == 0) sred[wid][tt * 16 + hi * 4 + i] = v;
        }
    __syncthreads();
    if (tid < 64) {
        float s = sred[0][tid] + sred[1][tid] + sred[2][tid] + sred[3][tid] + bV[0];
        scores[b * Tn + t0 + tid] = s;
    }
}

// K3: softmax over T per batch, in place.
__global__ __launch_bounds__(256) void k_softmax(const float* __restrict__ scores,
                                                 float* __restrict__ attn) {
    const int b = blockIdx.x, tid = threadIdx.x;
    __shared__ float redm[4];
    __shared__ float reds[4];
    float s[16];
    float m = -1e30f;
    #pragma unroll
    for (int k = 0; k < 16; ++k) {
        s[k] = scores[b * Tn + k * 256 + tid];
        m = fmaxf(m, s[k]);
    }
    #pragma unroll
    for (int off = 32; off > 0; off >>= 1) m = fmaxf(m, __shfl_xor(m, off, 64));
    const int wid = tid >> 6;
    if ((tid & 63) == 0) redm[wid] = m;
    __syncthreads();
    m = fmaxf(fmaxf(redm[0], redm[1]), fmaxf(redm[2], redm[3]));
    float sum = 0.f;
    #pragma unroll
    for (int k = 0; k < 16; ++k) { s[k] = __expf(s[k] - m); sum += s[k]; }
    #pragma unroll
    for (int off = 32; off > 0; off >>= 1) sum += __shfl_xor(sum, off, 64);
    if ((tid & 63) == 0) reds[wid] = sum;
    __syncthreads();
    sum = reds[0] + reds[1] + reds[2] + reds[3];
    const float inv = 1.0f / sum;
    #pragma unroll
    for (int k = 0; k < 16; ++k) attn[b * Tn + k * 256 + tid] = s[k] * inv;
}

// K4: context partials, deterministic.
__global__ __launch_bounds__(256) void k_ctx_partial(const float* __restrict__ values,
                                                     const float* __restrict__ attn,
                                                     float* __restrict__ partial) {
    const int c = blockIdx.x, b = blockIdx.y, tid = threadIdx.x;
    const int d4 = (tid & 63) * 4, tg = tid >> 6;
    float4 a = make_float4(0.f, 0.f, 0.f, 0.f);
    const float* vbase = values + (size_t)b * Tn * Dn;
    const int tstart = c * (Tn / CTX_C);
    for (int t = tstart + tg; t < tstart + Tn / CTX_C; t += 4) {
        const float w = attn[b * Tn + t];  // wave-uniform
        const float4 v = *(const float4*)&vbase[(size_t)t * Dn + d4];
        a.x += w * v.x; a.y += w * v.y; a.z += w * v.z; a.w += w * v.w;
    }
    __shared__ float4 red[4][64];
    red[tg][tid & 63] = a;
    __syncthreads();
    if (tg == 0) {
        const float4 r0 = red[0][tid], r1 = red[1][tid], r2 = red[2][tid], r3 = red[3][tid];
        a.x = r0.x + r1.x + r2.x + r3.x;
        a.y = r0.y + r1.y + r2.y + r3.y;
        a.z = r0.z + r1.z + r2.z + r3.z;
        a.w = r0.w + r1.w + r2.w + r3.w;
        *(float4*)&partial[((size_t)b * CTX_C + c) * Dn + d4] = a;
    }
}

// K5: reduce the CTX_C partials per batch.
__global__ __launch_bounds__(256) void k_ctx_final(const float* __restrict__ partial,
                                                   float* __restrict__ context) {
    const int b = blockIdx.x, d = threadIdx.x;
    float a = 0.f;
    #pragma unroll
    for (int c = 0; c < CTX_C; ++c) a += partial[((size_t)b * CTX_C + c) * Dn + d];
    context[b * Dn + d] = a;
}

extern "C" void kernel_launch(void* const* d_in, const int* in_sizes, int n_in,
                              void* d_out, int out_size, void* d_ws, size_t ws_size,
                              hipStream_t stream) {
    const float* query  = (const float*)d_in[0];
    const float* values = (const float*)d_in[1];
    const float* W1     = (const float*)d_in[2];
    const float* b1     = (const float*)d_in[3];
    const float* W2     = (const float*)d_in[4];
    const float* b2     = (const float*)d_in[5];
    const float* Vw     = (const float*)d_in[6];
    const float* bV     = (const float*)d_in[7];

    float* context = (float*)d_out;            // [B,D]
    float* attn    = (float*)d_out + Bn * Dn;  // [B,T,1] — score scratch then softmax in place
    float*  partial = (float*)d_ws;                         // [B, CTX_C, D]
    float*  qb      = partial + Bn * CTX_C * Dn;            // [B, U]
    ushort* W1T     = (ushort*)(qb + Bn * Un);              // [U, D] bf16

    k_w1t<<<dim3(Un), dim3(Dn), 0, stream>>>(W1, W1T);
    k_qproj<<<dim3(Bn), dim3(256), 0, stream>>>(query, W2, b1, b2, qb);
    k_score<<<dim3(Tn / 64, Bn), dim3(256), 0, stream>>>(values, W1T, qb, Vw, bV, attn);
    k_softmax<<<dim3(Bn), dim3(256), 0, stream>>>(attn, attn);
    k_ctx_partial<<<dim3(CTX_C, Bn), dim3(256), 0, stream>>>(values, attn, partial);
    k_ctx_final<<<dim3(Bn), dim3(256), 0, stream>>>(partial, context);
}